// Round 6
// baseline (601.216 us; speedup 1.0000x reference)
//
#include <hip/hip_runtime.h>
#include <hip/hip_bf16.h>

#define B_ 4
#define S_ 4096
#define D_ 256

typedef __attribute__((ext_vector_type(8))) short bf16x8;
typedef __attribute__((ext_vector_type(4))) short short4v;
typedef __attribute__((ext_vector_type(4))) float f32x4;

// round-to-nearest-even f32 -> bf16 bits (inputs finite)
static __device__ __forceinline__ unsigned short f2bf(float f) {
    unsigned int u = __float_as_uint(f);
    u += 0x7fffu + ((u >> 16) & 1u);
    return (unsigned short)(u >> 16);
}
static __device__ __forceinline__ float bf2f(unsigned short h) {
    return __uint_as_float(((unsigned int)h) << 16);
}

// ---------------------------------------------------------------------------
// Kernel 1: QKV = X @ W^T + b, f32 in, bf16 out (all to ws).
// Q,K row-major [b*S+s][256]; V transposed Vt[b][d][s].
// Tiles: BM=64, BN=64, BK=64; 4 waves (2x2), each 32x32 via 16x16x32 MFMA.
// ---------------------------------------------------------------------------
__global__ __launch_bounds__(256) void qkv_proj(
    const float* __restrict__ X, const float* __restrict__ W,
    const float* __restrict__ bias,
    unsigned short* __restrict__ Qb, unsigned short* __restrict__ Kb,
    unsigned short* __restrict__ Vt)
{
    __shared__ __align__(16) unsigned short As[64 * 64];
    __shared__ __align__(16) unsigned short Bs[64 * 64];

    const int tid  = threadIdx.x;
    const int lane = tid & 63;
    const int wid  = tid >> 6;
    const int wm   = wid >> 1, wn = wid & 1;
    const int c    = lane & 15, q4 = lane >> 4;
    const int gm0  = blockIdx.x * 64;   // row tile in M = b*S+s
    const int gn0  = blockIdx.y * 64;   // col tile in E = 768
    const int sr   = tid >> 2;          // staging row 0..63
    const int sc   = (tid & 3) * 16;    // staging col {0,16,32,48}

    f32x4 acc[2][2] = {};

    for (int kt = 0; kt < 4; ++kt) {
        const int k0 = kt * 64;
        // ---- stage X and W tiles (f32 -> bf16, swizzled) ----
        {
            const float4* ga = (const float4*)(X + (size_t)(gm0 + sr) * D_ + k0 + sc);
            const float4* gb = (const float4*)(W + (size_t)(gn0 + sr) * D_ + k0 + sc);
            float4 a0 = ga[0], a1 = ga[1], a2 = ga[2], a3 = ga[3];
            float4 b0 = gb[0], b1 = gb[1], b2 = gb[2], b3 = gb[3];
            float af[16] = {a0.x,a0.y,a0.z,a0.w, a1.x,a1.y,a1.z,a1.w,
                            a2.x,a2.y,a2.z,a2.w, a3.x,a3.y,a3.z,a3.w};
            float bf[16] = {b0.x,b0.y,b0.z,b0.w, b1.x,b1.y,b1.z,b1.w,
                            b2.x,b2.y,b2.z,b2.w, b3.x,b3.y,b3.z,b3.w};
            bf16x8 av0, av1, bv0, bv1;
            #pragma unroll
            for (int j = 0; j < 8; ++j) {
                av0[j] = (short)f2bf(af[j]);     av1[j] = (short)f2bf(af[8 + j]);
                bv0[j] = (short)f2bf(bf[j]);     bv1[j] = (short)f2bf(bf[8 + j]);
            }
            const int sw = (sr & 7) << 3;
            *(bf16x8*)&As[sr * 64 + ((sc + 0) ^ sw)] = av0;
            *(bf16x8*)&As[sr * 64 + ((sc + 8) ^ sw)] = av1;
            *(bf16x8*)&Bs[sr * 64 + ((sc + 0) ^ sw)] = bv0;
            *(bf16x8*)&Bs[sr * 64 + ((sc + 8) ^ sw)] = bv1;
        }
        __syncthreads();
        // ---- MFMA over this K-slab ----
        const int sw = (c & 7) << 3;   // rows read below are (mult of 8) + c
        #pragma unroll
        for (int kk = 0; kk < 64; kk += 32) {
            bf16x8 afr[2], bfr[2];
            #pragma unroll
            for (int mf = 0; mf < 2; ++mf) {
                const int row = wm * 32 + mf * 16 + c;
                afr[mf] = *(const bf16x8*)&As[row * 64 + ((kk + 8 * q4) ^ sw)];
            }
            #pragma unroll
            for (int nf = 0; nf < 2; ++nf) {
                const int row = wn * 32 + nf * 16 + c;
                bfr[nf] = *(const bf16x8*)&Bs[row * 64 + ((kk + 8 * q4) ^ sw)];
            }
            #pragma unroll
            for (int mf = 0; mf < 2; ++mf)
                #pragma unroll
                for (int nf = 0; nf < 2; ++nf)
                    acc[mf][nf] = __builtin_amdgcn_mfma_f32_16x16x32_bf16(
                        afr[mf], bfr[nf], acc[mf][nf], 0, 0, 0);
        }
        __syncthreads();
    }

    // ---- epilogue: +bias, route to Q / K / Vt ----
    const int b  = gm0 >> 12;
    const int s0 = gm0 & 4095;
    #pragma unroll
    for (int mf = 0; mf < 2; ++mf) {
        #pragma unroll
        for (int nf = 0; nf < 2; ++nf) {
            const int e  = gn0 + wn * 32 + nf * 16 + c;
            const float bv = bias[e];
            const int srow0 = s0 + wm * 32 + mf * 16 + 4 * q4;  // +i
            if (e < 256) {
                #pragma unroll
                for (int i = 0; i < 4; ++i)
                    Qb[((size_t)b * S_ + srow0 + i) * D_ + e] =
                        f2bf(acc[mf][nf][i] + bv);
            } else if (e < 512) {
                #pragma unroll
                for (int i = 0; i < 4; ++i)
                    Kb[((size_t)b * S_ + srow0 + i) * D_ + (e - 256)] =
                        f2bf(acc[mf][nf][i] + bv);
            } else {
                short4v pv;
                #pragma unroll
                for (int i = 0; i < 4; ++i)
                    pv[i] = (short)f2bf(acc[mf][nf][i] + bv);
                *(short4v*)&Vt[((size_t)(b * D_ + (e - 512))) * S_ + srow0] = pv;
            }
        }
    }
}

// ---------------------------------------------------------------------------
// Kernel 2: flash attention fwd. 4 waves/block, 16 Q rows/wave, KV step = 32.
// Classic online softmax; l accumulated from the SAME bf16-rounded P fed to
// the PV MFMA. OUTPUT IS FLOAT32 (the reference's output dtype).
// ---------------------------------------------------------------------------
__global__ __launch_bounds__(256) void attn_fwd(
    const unsigned short* __restrict__ Qb, const unsigned short* __restrict__ Kb,
    const unsigned short* __restrict__ Vt, float* __restrict__ Out)
{
    __shared__ __align__(16) unsigned short Plds[4][16 * 48];

    const int bid = blockIdx.x;
    const int b   = bid >> 6;
    const int qt  = bid & 63;
    const int tid = threadIdx.x;
    const int wid = tid >> 6, lane = tid & 63;
    const int c   = lane & 15, q4 = lane >> 4;
    const int q0  = qt * 64 + wid * 16;

    // Q fragments (A operand); 1/sqrt(D) folded into exp2 constant C
    bf16x8 qf[8];
    {
        const size_t qbase = ((size_t)(b * S_ + q0 + c)) * D_ + 8 * q4;
        #pragma unroll
        for (int f = 0; f < 8; ++f)
            qf[f] = *(const bf16x8*)&Qb[qbase + f * 32];
    }

    f32x4 o[16] = {};
    float m0[4], l0[4];
    #pragma unroll
    for (int i = 0; i < 4; ++i) { m0[i] = -1.0e30f; l0[i] = 0.0f; }

    const float C = 0.09016844005556021f;   // log2(e) / sqrt(256)

    for (int kv = 0; kv < S_; kv += 32) {
        // ---- raw scores S[16 q][32 k] ----
        f32x4 sacc[2] = {};
        #pragma unroll
        for (int kc = 0; kc < 2; ++kc) {
            const size_t kb = ((size_t)(b * S_ + kv + kc * 16 + c)) * D_ + 8 * q4;
            #pragma unroll
            for (int f = 0; f < 8; ++f) {
                bf16x8 kf = *(const bf16x8*)&Kb[kb + f * 32];
                sacc[kc] = __builtin_amdgcn_mfma_f32_16x16x32_bf16(
                    qf[f], kf, sacc[kc], 0, 0, 0);
            }
        }
        // ---- tile max per row (rows 4*q4+i live across 16 lanes) ----
        float rmax[4];
        #pragma unroll
        for (int i = 0; i < 4; ++i) rmax[i] = fmaxf(sacc[0][i], sacc[1][i]);
        #pragma unroll
        for (int d = 1; d < 16; d <<= 1)
            #pragma unroll
            for (int i = 0; i < 4; ++i)
                rmax[i] = fmaxf(rmax[i], __shfl_xor(rmax[i], d));

        // ---- classic rescale ----
        bool grow = false;
        #pragma unroll
        for (int i = 0; i < 4; ++i) grow = grow || (rmax[i] > m0[i]);
        if (__any(grow)) {
            #pragma unroll
            for (int i = 0; i < 4; ++i) {
                const float mn = fmaxf(m0[i], rmax[i]);
                const float corr = exp2f((m0[i] - mn) * C);
                m0[i] = mn;
                l0[i] *= corr;
                #pragma unroll
                for (int dt = 0; dt < 16; ++dt) o[dt][i] *= corr;
            }
        }

        // ---- P = exp(S - m); l from the bf16-rounded P ----
        float rsum[4] = {0.f, 0.f, 0.f, 0.f};
        unsigned short pb[2][4];
        #pragma unroll
        for (int kc = 0; kc < 2; ++kc)
            #pragma unroll
            for (int i = 0; i < 4; ++i) {
                const float p = exp2f((sacc[kc][i] - m0[i]) * C);
                const unsigned short us = f2bf(p);
                pb[kc][i] = us;
                rsum[i] += bf2f(us);
            }
        #pragma unroll
        for (int d = 1; d < 16; d <<= 1)
            #pragma unroll
            for (int i = 0; i < 4; ++i) rsum[i] += __shfl_xor(rsum[i], d);
        #pragma unroll
        for (int i = 0; i < 4; ++i) l0[i] += rsum[i];

        // ---- P -> LDS (transpose to A-operand layout), per-wave buffer ----
        #pragma unroll
        for (int kc = 0; kc < 2; ++kc)
            #pragma unroll
            for (int i = 0; i < 4; ++i)
                Plds[wid][(4 * q4 + i) * 48 + kc * 16 + c] = pb[kc][i];
        __syncthreads();
        const bf16x8 pf = *(const bf16x8*)&Plds[wid][c * 48 + 8 * q4];

        // ---- O += P @ V (Vt gives 8 consecutive keys per lane) ----
        const size_t vb = ((size_t)(b * D_ + c)) * S_ + kv + 8 * q4;
        #pragma unroll
        for (int dt = 0; dt < 16; ++dt) {
            bf16x8 vf = *(const bf16x8*)&Vt[vb + (size_t)dt * 16 * S_];
            o[dt] = __builtin_amdgcn_mfma_f32_16x16x32_bf16(pf, vf, o[dt], 0, 0, 0);
        }
        __syncthreads();
    }

    // ---- epilogue: O/l -> FLOAT32 out ----
    float inv[4];
    #pragma unroll
    for (int i = 0; i < 4; ++i) inv[i] = 1.0f / l0[i];
    #pragma unroll
    for (int dt = 0; dt < 16; ++dt)
        #pragma unroll
        for (int i = 0; i < 4; ++i)
            Out[((size_t)(b * S_ + q0 + 4 * q4 + i)) * D_ + dt * 16 + c] =
                o[dt][i] * inv[i];
}

extern "C" void kernel_launch(void* const* d_in, const int* in_sizes, int n_in,
                              void* d_out, int out_size, void* d_ws, size_t ws_size,
                              hipStream_t stream) {
    (void)out_size; (void)ws_size;
    // Bind inputs by element count (robust to ordering):
    const void *Xp = nullptr, *Wp = nullptr, *bp = nullptr;
    for (int i = 0; i < n_in; ++i) {
        if      (in_sizes[i] == B_ * S_ * D_) Xp = d_in[i];
        else if (in_sizes[i] == 3 * D_ * D_)  Wp = d_in[i];
        else if (in_sizes[i] == 3 * D_)       bp = d_in[i];
    }
    if (!Xp) Xp = d_in[0];
    if (!Wp) Wp = d_in[1];
    if (!bp) bp = d_in[2];

    float* Out = (float*)d_out;                                 // [B*S][256] FLOAT32

    unsigned short* Qb = (unsigned short*)d_ws;                 // [B*S][256] bf16 (8 MiB)
    unsigned short* Kb = Qb + (size_t)B_ * S_ * D_;             // [B*S][256] bf16 (8 MiB)
    unsigned short* Vt = Kb + (size_t)B_ * S_ * D_;             // [B][256][S] bf16 (8 MiB)
    // ws needed: 24 MiB (round 1 ran with this footprint)

    dim3 pgrid(256, 12);   // M/64 x E/64
    qkv_proj<<<pgrid, 256, 0, stream>>>((const float*)Xp, (const float*)Wp,
                                        (const float*)bp, Qb, Kb, Vt);
    attn_fwd<<<256, 256, 0, stream>>>(Qb, Kb, Vt, Out);
}

// Round 7
// 492.928 us; speedup vs baseline: 1.2197x; 1.2197x over previous
//
#include <hip/hip_runtime.h>
#include <hip/hip_bf16.h>

#define B_ 4
#define S_ 4096
#define D_ 256

typedef __attribute__((ext_vector_type(8))) short bf16x8;
typedef __attribute__((ext_vector_type(4))) short short4v;
typedef __attribute__((ext_vector_type(4))) float f32x4;

// round-to-nearest-even f32 -> bf16 bits (inputs finite)
static __device__ __forceinline__ unsigned short f2bf(float f) {
    unsigned int u = __float_as_uint(f);
    u += 0x7fffu + ((u >> 16) & 1u);
    return (unsigned short)(u >> 16);
}
static __device__ __forceinline__ float bf2f(unsigned short h) {
    return __uint_as_float(((unsigned int)h) << 16);
}

// ---------------------------------------------------------------------------
// Kernel 1 (unchanged, certified): QKV = X @ W^T + b, f32 in, bf16 out.
// Q,K row-major [b*S+s][256]; V transposed Vt[b][d][s].
// ---------------------------------------------------------------------------
__global__ __launch_bounds__(256) void qkv_proj(
    const float* __restrict__ X, const float* __restrict__ W,
    const float* __restrict__ bias,
    unsigned short* __restrict__ Qb, unsigned short* __restrict__ Kb,
    unsigned short* __restrict__ Vt)
{
    __shared__ __align__(16) unsigned short As[64 * 64];
    __shared__ __align__(16) unsigned short Bs[64 * 64];

    const int tid  = threadIdx.x;
    const int lane = tid & 63;
    const int wid  = tid >> 6;
    const int wm   = wid >> 1, wn = wid & 1;
    const int c    = lane & 15, q4 = lane >> 4;
    const int gm0  = blockIdx.x * 64;
    const int gn0  = blockIdx.y * 64;
    const int sr   = tid >> 2;
    const int sc   = (tid & 3) * 16;

    f32x4 acc[2][2] = {};

    for (int kt = 0; kt < 4; ++kt) {
        const int k0 = kt * 64;
        {
            const float4* ga = (const float4*)(X + (size_t)(gm0 + sr) * D_ + k0 + sc);
            const float4* gb = (const float4*)(W + (size_t)(gn0 + sr) * D_ + k0 + sc);
            float4 a0 = ga[0], a1 = ga[1], a2 = ga[2], a3 = ga[3];
            float4 b0 = gb[0], b1 = gb[1], b2 = gb[2], b3 = gb[3];
            float af[16] = {a0.x,a0.y,a0.z,a0.w, a1.x,a1.y,a1.z,a1.w,
                            a2.x,a2.y,a2.z,a2.w, a3.x,a3.y,a3.z,a3.w};
            float bf[16] = {b0.x,b0.y,b0.z,b0.w, b1.x,b1.y,b1.z,b1.w,
                            b2.x,b2.y,b2.z,b2.w, b3.x,b3.y,b3.z,b3.w};
            bf16x8 av0, av1, bv0, bv1;
            #pragma unroll
            for (int j = 0; j < 8; ++j) {
                av0[j] = (short)f2bf(af[j]);     av1[j] = (short)f2bf(af[8 + j]);
                bv0[j] = (short)f2bf(bf[j]);     bv1[j] = (short)f2bf(bf[8 + j]);
            }
            const int sw = (sr & 7) << 3;
            *(bf16x8*)&As[sr * 64 + ((sc + 0) ^ sw)] = av0;
            *(bf16x8*)&As[sr * 64 + ((sc + 8) ^ sw)] = av1;
            *(bf16x8*)&Bs[sr * 64 + ((sc + 0) ^ sw)] = bv0;
            *(bf16x8*)&Bs[sr * 64 + ((sc + 8) ^ sw)] = bv1;
        }
        __syncthreads();
        const int sw = (c & 7) << 3;
        #pragma unroll
        for (int kk = 0; kk < 64; kk += 32) {
            bf16x8 afr[2], bfr[2];
            #pragma unroll
            for (int mf = 0; mf < 2; ++mf) {
                const int row = wm * 32 + mf * 16 + c;
                afr[mf] = *(const bf16x8*)&As[row * 64 + ((kk + 8 * q4) ^ sw)];
            }
            #pragma unroll
            for (int nf = 0; nf < 2; ++nf) {
                const int row = wn * 32 + nf * 16 + c;
                bfr[nf] = *(const bf16x8*)&Bs[row * 64 + ((kk + 8 * q4) ^ sw)];
            }
            #pragma unroll
            for (int mf = 0; mf < 2; ++mf)
                #pragma unroll
                for (int nf = 0; nf < 2; ++nf)
                    acc[mf][nf] = __builtin_amdgcn_mfma_f32_16x16x32_bf16(
                        afr[mf], bfr[nf], acc[mf][nf], 0, 0, 0);
        }
        __syncthreads();
    }

    const int b  = gm0 >> 12;
    const int s0 = gm0 & 4095;
    #pragma unroll
    for (int mf = 0; mf < 2; ++mf) {
        #pragma unroll
        for (int nf = 0; nf < 2; ++nf) {
            const int e  = gn0 + wn * 32 + nf * 16 + c;
            const float bv = bias[e];
            const int srow0 = s0 + wm * 32 + mf * 16 + 4 * q4;
            if (e < 256) {
                #pragma unroll
                for (int i = 0; i < 4; ++i)
                    Qb[((size_t)b * S_ + srow0 + i) * D_ + e] =
                        f2bf(acc[mf][nf][i] + bv);
            } else if (e < 512) {
                #pragma unroll
                for (int i = 0; i < 4; ++i)
                    Kb[((size_t)b * S_ + srow0 + i) * D_ + (e - 256)] =
                        f2bf(acc[mf][nf][i] + bv);
            } else {
                short4v pv;
                #pragma unroll
                for (int i = 0; i < 4; ++i)
                    pv[i] = (short)f2bf(acc[mf][nf][i] + bv);
                *(short4v*)&Vt[((size_t)(b * D_ + (e - 512))) * S_ + srow0] = pv;
            }
        }
    }
}

// ---------------------------------------------------------------------------
// One flash step over 32 keys. Per-wave/per-chain LDS slice; NO barriers
// (within-wave lgkmcnt ordering suffices). l from bf16-rounded P.
// ---------------------------------------------------------------------------
__device__ __forceinline__ void attn_step(
    const unsigned short* __restrict__ Kbb, const unsigned short* __restrict__ Vtb,
    int kv, const bf16x8 qf[8], int c, int q4,
    unsigned short* plds, float m0[4], float l0[4], f32x4 o[16])
{
    const float C = 0.09016844005556021f;   // log2(e) / sqrt(256)

    f32x4 sacc[2] = {};
    #pragma unroll
    for (int kc = 0; kc < 2; ++kc) {
        const unsigned short* kp = Kbb + (size_t)(kv + kc * 16 + c) * D_ + 8 * q4;
        #pragma unroll
        for (int f = 0; f < 8; ++f) {
            bf16x8 kf = *(const bf16x8*)(kp + f * 32);
            sacc[kc] = __builtin_amdgcn_mfma_f32_16x16x32_bf16(qf[f], kf, sacc[kc], 0, 0, 0);
        }
    }

    float rmax[4];
    #pragma unroll
    for (int i = 0; i < 4; ++i) rmax[i] = fmaxf(sacc[0][i], sacc[1][i]);
    #pragma unroll
    for (int d = 1; d < 16; d <<= 1)
        #pragma unroll
        for (int i = 0; i < 4; ++i)
            rmax[i] = fmaxf(rmax[i], __shfl_xor(rmax[i], d));

    bool grow = false;
    #pragma unroll
    for (int i = 0; i < 4; ++i) grow = grow || (rmax[i] > m0[i]);
    if (__any(grow)) {
        #pragma unroll
        for (int i = 0; i < 4; ++i) {
            const float mn = fmaxf(m0[i], rmax[i]);
            const float corr = exp2f((m0[i] - mn) * C);
            m0[i] = mn;
            l0[i] *= corr;
            #pragma unroll
            for (int dt = 0; dt < 16; ++dt) o[dt][i] *= corr;
        }
    }

    float rsum[4] = {0.f, 0.f, 0.f, 0.f};
    unsigned short pb[2][4];
    #pragma unroll
    for (int kc = 0; kc < 2; ++kc)
        #pragma unroll
        for (int i = 0; i < 4; ++i) {
            const float p = exp2f((sacc[kc][i] - m0[i]) * C);
            const unsigned short us = f2bf(p);
            pb[kc][i] = us;
            rsum[i] += bf2f(us);
        }
    #pragma unroll
    for (int d = 1; d < 16; d <<= 1)
        #pragma unroll
        for (int i = 0; i < 4; ++i) rsum[i] += __shfl_xor(rsum[i], d);
    #pragma unroll
    for (int i = 0; i < 4; ++i) l0[i] += rsum[i];

    // P transpose through per-wave/per-chain LDS slice (no barriers).
    #pragma unroll
    for (int kc = 0; kc < 2; ++kc)
        #pragma unroll
        for (int i = 0; i < 4; ++i)
            plds[(4 * q4 + i) * 48 + kc * 16 + c] = pb[kc][i];
    const bf16x8 pf = *(const bf16x8*)&plds[c * 48 + 8 * q4];

    const unsigned short* vp = Vtb + (size_t)c * S_ + kv + 8 * q4;
    #pragma unroll
    for (int dt = 0; dt < 16; ++dt) {
        bf16x8 vf = *(const bf16x8*)(vp + (size_t)dt * 16 * S_);
        o[dt] = __builtin_amdgcn_mfma_f32_16x16x32_bf16(pf, vf, o[dt], 0, 0, 0);
    }
}

// ---------------------------------------------------------------------------
// Kernel 2: flash attention, 4 waves/block, 16 Q rows/wave, KV step 32.
// DUAL-CHAIN ILP: each wave runs two independent KV halves (0..2048, 2048..
// 4096) with separate (m,l,O) state, merged in-register at the end. No
// __syncthreads anywhere (LDS slices are per-wave).
// ---------------------------------------------------------------------------
__global__ __launch_bounds__(256) void attn_fwd(
    const unsigned short* __restrict__ Qb, const unsigned short* __restrict__ Kb,
    const unsigned short* __restrict__ Vt, float* __restrict__ Out)
{
    __shared__ __align__(16) unsigned short Plds[4][2][16 * 48];

    const int bid = blockIdx.x;
    const int b   = bid >> 6;
    const int qt  = bid & 63;
    const int tid = threadIdx.x;
    const int wid = tid >> 6, lane = tid & 63;
    const int c   = lane & 15, q4 = lane >> 4;
    const int q0  = qt * 64 + wid * 16;

    bf16x8 qf[8];
    {
        const size_t qbase = ((size_t)(b * S_ + q0 + c)) * D_ + 8 * q4;
        #pragma unroll
        for (int f = 0; f < 8; ++f)
            qf[f] = *(const bf16x8*)&Qb[qbase + f * 32];
    }

    const unsigned short* Kbb = Kb + (size_t)b * S_ * D_;
    const unsigned short* Vtb = Vt + (size_t)b * D_ * S_;

    f32x4 oA[16] = {}, oB[16] = {};
    float mA[4], lA[4], mB[4], lB[4];
    #pragma unroll
    for (int i = 0; i < 4; ++i) {
        mA[i] = -1.0e30f; lA[i] = 0.0f;
        mB[i] = -1.0e30f; lB[i] = 0.0f;
    }

    unsigned short* pldsA = &Plds[wid][0][0];
    unsigned short* pldsB = &Plds[wid][1][0];

    for (int kv = 0; kv < S_ / 2; kv += 32) {
        attn_step(Kbb, Vtb, kv,            qf, c, q4, pldsA, mA, lA, oA);
        attn_step(Kbb, Vtb, kv + S_ / 2,   qf, c, q4, pldsB, mB, lB, oB);
    }

    // ---- merge chains + epilogue (f32 out) ----
    const float C = 0.09016844005556021f;
    #pragma unroll
    for (int i = 0; i < 4; ++i) {
        const float mm = fmaxf(mA[i], mB[i]);
        const float ca = exp2f((mA[i] - mm) * C);
        const float cb = exp2f((mB[i] - mm) * C);
        const float inv = 1.0f / (lA[i] * ca + lB[i] * cb);
        #pragma unroll
        for (int dt = 0; dt < 16; ++dt) {
            const float val = (oA[dt][i] * ca + oB[dt][i] * cb) * inv;
            Out[((size_t)(b * S_ + q0 + 4 * q4 + i)) * D_ + dt * 16 + c] = val;
        }
    }
}

extern "C" void kernel_launch(void* const* d_in, const int* in_sizes, int n_in,
                              void* d_out, int out_size, void* d_ws, size_t ws_size,
                              hipStream_t stream) {
    (void)out_size; (void)ws_size;
    const void *Xp = nullptr, *Wp = nullptr, *bp = nullptr;
    for (int i = 0; i < n_in; ++i) {
        if      (in_sizes[i] == B_ * S_ * D_) Xp = d_in[i];
        else if (in_sizes[i] == 3 * D_ * D_)  Wp = d_in[i];
        else if (in_sizes[i] == 3 * D_)       bp = d_in[i];
    }
    if (!Xp) Xp = d_in[0];
    if (!Wp) Wp = d_in[1];
    if (!bp) bp = d_in[2];

    float* Out = (float*)d_out;                                 // [B*S][256] f32

    unsigned short* Qb = (unsigned short*)d_ws;                 // 8 MiB
    unsigned short* Kb = Qb + (size_t)B_ * S_ * D_;             // 8 MiB
    unsigned short* Vt = Kb + (size_t)B_ * S_ * D_;             // 8 MiB
    // ws needed: 24 MiB

    dim3 pgrid(256, 12);
    qkv_proj<<<pgrid, 256, 0, stream>>>((const float*)Xp, (const float*)Wp,
                                        (const float*)bp, Qb, Kb, Vt);
    attn_fwd<<<256, 256, 0, stream>>>(Qb, Kb, Vt, Out);
}